// Round 20
// baseline (255.909 us; speedup 1.0000x reference)
//
#include <hip/hip_runtime.h>

typedef unsigned short u16;
typedef unsigned char u8;
typedef __attribute__((ext_vector_type(8))) short bf16x8;
typedef __attribute__((ext_vector_type(4))) float f32x4;
typedef __attribute__((ext_vector_type(4))) int i32x4;
typedef __attribute__((ext_vector_type(8))) int i32x8;

__device__ __forceinline__ u16 f2bf(float f) {
  unsigned u = __builtin_bit_cast(unsigned, f);
  u += 0x7fffu + ((u >> 16) & 1u);
  return (u16)(u >> 16);
}

__device__ __forceinline__ float bf2f(u16 h) {
  unsigned u = ((unsigned)h) << 16;
  return __builtin_bit_cast(float, u);
}

__device__ __forceinline__ unsigned pkbf(float lo, float hi) {
  unsigned r;
  asm("v_cvt_pk_bf16_f32 %0, %1, %2" : "=v"(r) : "v"(lo), "v"(hi));
  return r;
}

__device__ __forceinline__ void gll16(const void* g, void* l) {
  __builtin_amdgcn_global_load_lds((const __attribute__((address_space(1))) void*)g,
                                   (__attribute__((address_space(3))) void*)l, 16, 0, 0);
}

// MX fp8 MFMA with unity scales (e8m0 127 = 2^0): numerically plain fp8, 2.28x rate.
__device__ __forceinline__ f32x4 mfma_fp8_k128(i32x8 a, i32x8 b, f32x4 c) {
  return __builtin_amdgcn_mfma_scale_f32_16x16x128_f8f6f4(
      a, b, c, 0, 0, 0, 0x7f7f7f7f, 0, 0x7f7f7f7f);
}

// ---- prep: x->bf16 + x->fp8  |  Wq/Wk transpose (bf16) + Wv transpose (fp8)  |  bias ----
__global__ void prep_k(const float* __restrict__ x, u16* __restrict__ xb, u8* __restrict__ xf8,
                       const float* __restrict__ Wq, const float* __restrict__ Wk,
                       const float* __restrict__ Wv, u16* __restrict__ wt, u8* __restrict__ wv8,
                       const float* __restrict__ bq, const float* __restrict__ bk,
                       const float* __restrict__ bv, float* __restrict__ bc) {
  __shared__ float tile[64][65];
  const int b = blockIdx.x;
  const int t = threadIdx.x;
  if (b < 16384) {           // x -> bf16 + fp8
    const size_t i = ((size_t)b * 256 + t) * 8;
    float4 a = *(const float4*)(x + i);
    float4 c = *(const float4*)(x + i + 4);
    uint4 u;
    u.x = pkbf(a.x, a.y);
    u.y = pkbf(a.z, a.w);
    u.z = pkbf(c.x, c.y);
    u.w = pkbf(c.z, c.w);
    *(uint4*)(xb + i) = u;
    uint2 v;
    unsigned p0 = __builtin_amdgcn_cvt_pk_fp8_f32(a.x, a.y, 0, false);
    p0 = __builtin_amdgcn_cvt_pk_fp8_f32(a.z, a.w, p0, true);
    unsigned p1 = __builtin_amdgcn_cvt_pk_fp8_f32(c.x, c.y, 0, false);
    p1 = __builtin_amdgcn_cvt_pk_fp8_f32(c.z, c.w, p1, true);
    v.x = p0; v.y = p1;
    *(uint2*)(xf8 + i) = v;
  } else if (b < 16704) {    // weight transpose
    const int tb = b - 16384;
    const int n0 = (tb % 20) * 64;
    const int f0 = (tb / 20) * 64;
    const float* src; int ld, coff;
    if (n0 < 128)      { src = Wq; ld = 128;  coff = n0; }
    else if (n0 < 256) { src = Wk; ld = 128;  coff = n0 - 128; }
    else               { src = Wv; ld = 1024; coff = n0 - 256; }
    const int r = t >> 4, c4 = (t & 15) * 4;
    #pragma unroll
    for (int i = 0; i < 4; ++i) {
      float4 v = *(const float4*)(src + (size_t)(f0 + r + 16 * i) * ld + coff + c4);
      tile[r + 16 * i][c4 + 0] = v.x;
      tile[r + 16 * i][c4 + 1] = v.y;
      tile[r + 16 * i][c4 + 2] = v.z;
      tile[r + 16 * i][c4 + 3] = v.w;
    }
    __syncthreads();
    if (n0 < 256) {          // q/k rows -> wt bf16
      #pragma unroll
      for (int i = 0; i < 4; ++i) {
        const int nr = r + 16 * i;
        ushort4 h;
        h.x = f2bf(tile[c4 + 0][nr]);
        h.y = f2bf(tile[c4 + 1][nr]);
        h.z = f2bf(tile[c4 + 2][nr]);
        h.w = f2bf(tile[c4 + 3][nr]);
        *(ushort4*)(wt + (size_t)(n0 + nr) * 1024 + f0 + c4) = h;
      }
    } else {                 // v rows -> wv8 fp8
      #pragma unroll
      for (int i = 0; i < 4; ++i) {
        const int nr = r + 16 * i;
        unsigned v8 = __builtin_amdgcn_cvt_pk_fp8_f32(tile[c4 + 0][nr], tile[c4 + 1][nr], 0, false);
        v8 = __builtin_amdgcn_cvt_pk_fp8_f32(tile[c4 + 2][nr], tile[c4 + 3][nr], v8, true);
        *(unsigned*)(wv8 + (size_t)(n0 - 256 + nr) * 1024 + f0 + c4) = v8;
      }
    }
  } else {                   // bias concat
    for (int i = t; i < 1280; i += 256)
      bc[i] = (i < 128) ? bq[i] : ((i < 256) ? bk[i - 128] : bv[i - 256]);
  }
}

// ---------------- q/k GEMM: [32768,1024]bf16 @ [1024,256] + bias -> qk bf16 ----------------
__global__ __launch_bounds__(256, 2) void gemm_qk_k(
    const u16* __restrict__ xb, const u16* __restrict__ wt,
    const float* __restrict__ bc, u16* __restrict__ qkv) {
  __shared__ u16 sA[128 * 64];
  __shared__ u16 sB[128 * 64];
  char* sAc = (char*)sA;
  char* sBc = (char*)sB;
  const int t = threadIdx.x;
  const int w = t >> 6, lane = t & 63;
  const int wr = w >> 1, wc = w & 1;
  const int lm = lane & 15, lg = lane >> 4;
  const int bid = blockIdx.x;
  const int xcd = bid & 7, g = bid >> 3;
  const int mb = xcd + 8 * (g >> 1);
  const int nt = g & 1;
  const int m0 = mb * 128;
  const int n0 = nt * 128;
  const f32x4 FZ = {0.f, 0.f, 0.f, 0.f};

  const int brow = t >> 3;
  const int bcol = 8 * ((t & 7) ^ ((t >> 3) & 7));
  const int kswz = (lm & 7) << 4;
  const u16* ab = xb + (size_t)(m0 + brow) * 1024 + bcol;
  const u16* wb = wt + (size_t)(n0 + brow) * 1024 + bcol;

  f32x4 acc[4][4];
  #pragma unroll
  for (int mi = 0; mi < 4; ++mi)
    #pragma unroll
    for (int ni = 0; ni < 4; ++ni) acc[mi][ni] = FZ;

  for (int kt = 0; kt < 16; ++kt) {
    const int k0 = kt * 64;
    char* da = sAc + w * 1024;
    char* db = sBc + w * 1024;
    #pragma unroll
    for (int i = 0; i < 4; ++i) {
      gll16(ab + (size_t)(32 * i) * 1024 + k0, da + 4096 * i);
      gll16(wb + (size_t)(32 * i) * 1024 + k0, db + 4096 * i);
    }
    __syncthreads();
    #pragma unroll
    for (int ks = 0; ks < 2; ++ks) {
      const int ka = (ks * 64 + lg * 16) ^ kswz;
      bf16x8 aF[4], bF[4];
      #pragma unroll
      for (int mi = 0; mi < 4; ++mi)
        aF[mi] = *(const bf16x8*)(sAc + (wr * 64 + mi * 16 + lm) * 128 + ka);
      #pragma unroll
      for (int ni = 0; ni < 4; ++ni)
        bF[ni] = *(const bf16x8*)(sBc + (wc * 64 + ni * 16 + lm) * 128 + ka);
      #pragma unroll
      for (int mi = 0; mi < 4; ++mi)
        #pragma unroll
        for (int ni = 0; ni < 4; ++ni)
          acc[mi][ni] = __builtin_amdgcn_mfma_f32_16x16x32_bf16(aF[mi], bF[ni], acc[mi][ni], 0, 0, 0);
    }
    __syncthreads();
  }

  #pragma unroll
  for (int ni = 0; ni < 4; ++ni) {
    const int col = n0 + wc * 64 + ni * 16 + lm;
    const float bias = bc[col];
    #pragma unroll
    for (int mi = 0; mi < 4; ++mi) {
      const int r0 = m0 + wr * 64 + mi * 16 + lg * 4;
      #pragma unroll
      for (int j = 0; j < 4; ++j)
        qkv[(size_t)(r0 + j) * 256 + col] = f2bf(acc[mi][ni][j] + bias);
    }
  }
}

// ------- fused: even bids = v GEMM (MX fp8), odd bids = QK^T softmax -> P fp8 -------
// Interleaving lets compute-heavy softmax blocks fill the v-GEMM's memory-stall slots.
__global__ __launch_bounds__(256, 2) void vqs_k(
    const u8* __restrict__ xf8, const u8* __restrict__ wv8,
    const float* __restrict__ bc, u8* __restrict__ vt,
    const u16* __restrict__ qk, u8* __restrict__ P) {
  __shared__ char smem[32768];
  const int t = threadIdx.x;
  const int w = t >> 6, lane = t & 63;
  const int lm = lane & 15, lg = lane >> 4;
  const f32x4 FZ = {0.f, 0.f, 0.f, 0.f};
  const int sub = blockIdx.x >> 1;

  if ((blockIdx.x & 1) == 0) {
    // ---------- v GEMM (MX fp8 K=128): [32768,1024] @ [1024,1024] + bias -> vt fp8 ----------
    char* sAc = smem;
    char* sBc = smem + 16384;
    const int wr = w >> 1, wc = w & 1;
    const int xcd = sub & 7, g = sub >> 3;       // g in 0..255
    const int mb = xcd + 8 * (g >> 3);
    const int nt = g & 7;
    const int m0 = mb * 128;
    const int n0 = nt * 128;

    const int brow = t >> 3;
    const int bcol = 16 * ((t & 7) ^ ((t >> 3) & 7));
    const int kswz = (lm & 7) << 4;
    const u8* ab = xf8 + (size_t)(m0 + brow) * 1024 + bcol;
    const u8* wb = wv8 + (size_t)(n0 + brow) * 1024 + bcol;

    f32x4 acc[4][4];
    #pragma unroll
    for (int mi = 0; mi < 4; ++mi)
      #pragma unroll
      for (int ni = 0; ni < 4; ++ni) acc[mi][ni] = FZ;

    for (int kt = 0; kt < 8; ++kt) {
      const int k0 = kt * 128;
      #pragma unroll
      for (int i = 0; i < 4; ++i) {
        gll16(ab + (size_t)(32 * i) * 1024 + k0, sAc + i * 4096 + t * 16);
        gll16(wb + (size_t)(32 * i) * 1024 + k0, sBc + i * 4096 + t * 16);
      }
      __syncthreads();
      i32x8 bF[4];
      #pragma unroll
      for (int ni = 0; ni < 4; ++ni) {
        const char* rb = sBc + (wc * 64 + ni * 16 + lm) * 128;
        i32x4 lo = *(const i32x4*)(rb + ((lg * 32) ^ kswz));
        i32x4 hi = *(const i32x4*)(rb + ((lg * 32 + 16) ^ kswz));
        bF[ni] = __builtin_shufflevector(lo, hi, 0, 1, 2, 3, 4, 5, 6, 7);
      }
      #pragma unroll
      for (int mi = 0; mi < 4; ++mi) {
        const char* ra = sAc + (wr * 64 + mi * 16 + lm) * 128;
        i32x4 lo = *(const i32x4*)(ra + ((lg * 32) ^ kswz));
        i32x4 hi = *(const i32x4*)(ra + ((lg * 32 + 16) ^ kswz));
        i32x8 aF = __builtin_shufflevector(lo, hi, 0, 1, 2, 3, 4, 5, 6, 7);
        #pragma unroll
        for (int ni = 0; ni < 4; ++ni)
          acc[mi][ni] = mfma_fp8_k128(aF, bF[ni], acc[mi][ni]);
      }
      __syncthreads();
    }

    #pragma unroll
    for (int ni = 0; ni < 4; ++ni) {
      const int h = n0 + wc * 64 + ni * 16 + lm;
      const float bias = bc[256 + h];
      #pragma unroll
      for (int mi = 0; mi < 4; ++mi) {
        const int r0 = m0 + wr * 64 + mi * 16 + lg * 4;
        const int bg = r0 >> 10;
        const int sb = r0 & 1023;
        unsigned v32 = __builtin_amdgcn_cvt_pk_fp8_f32(acc[mi][ni][0] + bias,
                                                       acc[mi][ni][1] + bias, 0, false);
        v32 = __builtin_amdgcn_cvt_pk_fp8_f32(acc[mi][ni][2] + bias,
                                              acc[mi][ni][3] + bias, v32, true);
        *(unsigned*)(vt + ((size_t)(bg * 1024 + h) << 10) + sb) = v32;
      }
    }
  } else {
    // ---------- QK^T + exact softmax -> P fp8 (16 q rows, wave = 256-kv quarter) ----------
    float* smax = (float*)smem;         // [4][16]
    float* ssum = (float*)(smem + 256); // [4][16]
    const int bg = ((sub >> 9) & 3) * 8 + (sub & 7);
    const int qt = (sub >> 3) & 63;

    bf16x8 qf[4];
    #pragma unroll
    for (int ks = 0; ks < 4; ++ks)
      qf[ks] = *(const bf16x8*)(qk +
          (size_t)(bg * 1024 + qt * 16 + lm) * 256 + ks * 32 + lg * 8);

    f32x4 sc[16];
    #pragma unroll
    for (int ch = 0; ch < 16; ++ch) sc[ch] = FZ;
    const u16* kbase = qk + (size_t)(bg * 1024 + w * 256) * 256 + 128;
    #pragma unroll
    for (int ch = 0; ch < 16; ++ch) {
      bf16x8 kf[4];
      #pragma unroll
      for (int ks = 0; ks < 4; ++ks)
        kf[ks] = *(const bf16x8*)(kbase + (size_t)(ch * 16 + lm) * 256 + ks * 32 + lg * 8);
      #pragma unroll
      for (int ks = 0; ks < 4; ++ks)
        sc[ch] = __builtin_amdgcn_mfma_f32_16x16x32_bf16(kf[ks], qf[ks], sc[ch], 0, 0, 0);
    }

    float m = sc[0][0];
    #pragma unroll
    for (int ch = 0; ch < 16; ++ch)
      #pragma unroll
      for (int j = 0; j < 4; ++j) m = fmaxf(m, sc[ch][j]);
    m = fmaxf(m, __shfl_xor(m, 16));
    m = fmaxf(m, __shfl_xor(m, 32));
    if (lg == 0) smax[w * 16 + lm] = m;
    __syncthreads();
    float gm = fmaxf(fmaxf(smax[lm], smax[16 + lm]), fmaxf(smax[32 + lm], smax[48 + lm]));

    float ls = 0.f;
    #pragma unroll
    for (int ch = 0; ch < 16; ++ch) {
      f32x4 e;
      #pragma unroll
      for (int j = 0; j < 4; ++j) e[j] = __expf(sc[ch][j] - gm);
      sc[ch] = e;
      ls += (e[0] + e[1]) + (e[2] + e[3]);
    }
    ls += __shfl_xor(ls, 16);
    ls += __shfl_xor(ls, 32);
    if (lg == 0) ssum[w * 16 + lm] = ls;
    __syncthreads();
    const float inv = 1.0f / (((ssum[lm] + ssum[16 + lm]) + (ssum[32 + lm] + ssum[48 + lm])));

    const int s0 = (2 * (lg & 1)) * 16 + lm;
    const int s1 = s0 + 16;
    const bool lo = (lg < 2);
    u8* pr = P + ((size_t)(bg * 1024 + qt * 16 + lm) << 10) + w * 256 + lg * 8;
    #pragma unroll
    for (int c = 0; c < 8; ++c) {
      unsigned ue = __builtin_amdgcn_cvt_pk_fp8_f32(sc[2 * c][0] * inv, sc[2 * c][1] * inv, 0, false);
      ue = __builtin_amdgcn_cvt_pk_fp8_f32(sc[2 * c][2] * inv, sc[2 * c][3] * inv, ue, true);
      unsigned uo = __builtin_amdgcn_cvt_pk_fp8_f32(sc[2 * c + 1][0] * inv, sc[2 * c + 1][1] * inv, 0, false);
      uo = __builtin_amdgcn_cvt_pk_fp8_f32(sc[2 * c + 1][2] * inv, sc[2 * c + 1][3] * inv, uo, true);
      unsigned e0 = __shfl(ue, s0), o0 = __shfl(uo, s0);
      unsigned e1 = __shfl(ue, s1), o1 = __shfl(uo, s1);
      uint2 pw;
      pw.x = lo ? e0 : o0;
      pw.y = lo ? e1 : o1;
      *(uint2*)(pr + c * 32) = pw;
    }
  }
}

// ---------------- PV GEMM (MX fp8 K=128) + epilogue: out = gamma * (P @ V) + xb ----------------
__global__ __launch_bounds__(256, 2) void pv_k(
    const u8* __restrict__ P, const u8* __restrict__ vt,
    const u16* __restrict__ xb, const float* __restrict__ gam,
    float* __restrict__ out) {
  __shared__ u8 sA[128 * 128];
  __shared__ u8 sB[128 * 128];
  char* sAc = (char*)sA;
  char* sBc = (char*)sB;
  const int t = threadIdx.x;
  const int w = t >> 6, lane = t & 63;
  const int wr = w >> 1, wc = w & 1;
  const int lm = lane & 15, lg = lane >> 4;
  const int bid = blockIdx.x;
  const int bg = (((bid >> 9) & 3) << 3) | (bid & 7);
  const int qb = (bid >> 6) & 7;
  const int hb = (bid >> 3) & 7;
  const int m0 = qb * 128, n0 = hb * 128;
  const f32x4 FZ = {0.f, 0.f, 0.f, 0.f};

  const int brow = t >> 3;
  const int bcol = 16 * ((t & 7) ^ ((t >> 3) & 7));
  const int kswz = (lm & 7) << 4;
  const u8* pb = P + ((size_t)(bg * 1024 + m0 + brow) << 10) + bcol;
  const u8* wb = vt + ((size_t)(bg * 1024 + n0 + brow) << 10) + bcol;

  f32x4 acc[4][4];
  #pragma unroll
  for (int mi = 0; mi < 4; ++mi)
    #pragma unroll
    for (int ni = 0; ni < 4; ++ni) acc[mi][ni] = FZ;

  for (int kt = 0; kt < 8; ++kt) {
    const int k0 = kt * 128;
    #pragma unroll
    for (int i = 0; i < 4; ++i) {
      gll16(pb + (size_t)(32 * i) * 1024 + k0, sAc + i * 4096 + t * 16);
      gll16(wb + (size_t)(32 * i) * 1024 + k0, sBc + i * 4096 + t * 16);
    }
    __syncthreads();
    i32x8 bF[4];
    #pragma unroll
    for (int ni = 0; ni < 4; ++ni) {
      const char* rb = sBc + (wc * 64 + ni * 16 + lm) * 128;
      i32x4 lo = *(const i32x4*)(rb + ((lg * 32) ^ kswz));
      i32x4 hi = *(const i32x4*)(rb + ((lg * 32 + 16) ^ kswz));
      bF[ni] = __builtin_shufflevector(lo, hi, 0, 1, 2, 3, 4, 5, 6, 7);
    }
    #pragma unroll
    for (int mi = 0; mi < 4; ++mi) {
      const char* ra = sAc + (wr * 64 + mi * 16 + lm) * 128;
      i32x4 lo = *(const i32x4*)(ra + ((lg * 32) ^ kswz));
      i32x4 hi = *(const i32x4*)(ra + ((lg * 32 + 16) ^ kswz));
      i32x8 aF = __builtin_shufflevector(lo, hi, 0, 1, 2, 3, 4, 5, 6, 7);
      #pragma unroll
      for (int ni = 0; ni < 4; ++ni)
        acc[mi][ni] = mfma_fp8_k128(aF, bF[ni], acc[mi][ni]);
    }
    __syncthreads();
  }

  const float g0 = gam[0];
  #pragma unroll
  for (int mi = 0; mi < 4; ++mi)
    #pragma unroll
    for (int j = 0; j < 4; ++j) {
      const size_t row = (size_t)(bg * 1024 + m0 + wr * 64 + mi * 16 + lg * 4 + j);
      #pragma unroll
      for (int ni = 0; ni < 4; ++ni) {
        const int col = n0 + wc * 64 + ni * 16 + lm;
        const size_t idx = row * 1024 + col;
        __builtin_nontemporal_store(g0 * acc[mi][ni][j] + bf2f(xb[idx]), &out[idx]);
      }
    }
}

extern "C" void kernel_launch(void* const* d_in, const int* in_sizes, int n_in,
                              void* d_out, int out_size, void* d_ws, size_t ws_size,
                              hipStream_t stream) {
  const float* x  = (const float*)d_in[0];
  const float* Wq = (const float*)d_in[1];
  const float* bq = (const float*)d_in[2];
  const float* Wk = (const float*)d_in[3];
  const float* bk = (const float*)d_in[4];
  const float* Wv = (const float*)d_in[5];
  const float* bv = (const float*)d_in[6];
  const float* gm = (const float*)d_in[7];
  float* out = (float*)d_out;

  char* ws = (char*)d_ws;
  u16*   wt  = (u16*)(ws);                 // 524,288 B (q/k rows only)
  float* bc  = (float*)(ws + 524288);      // 5,120 B
  u16*   qk  = (u16*)(ws + 529408);        // 16,777,216 B
  u8*    vt  = (u8*)(ws + 17306624);       // 33,554,432 B (fp8)
  u8*    Pm  = (u8*)(ws + 50861056);       // 33,554,432 B (fp8)
  u16*   xb  = (u16*)(ws + 84415488);      // 67,108,864 B (bf16)
  u8*    xf8 = (u8*)(ws + 151524352);      // 33,554,432 B (fp8)
  u8*    wv8 = (u8*)(ws + 185078784);      // 1,048,576 B

  prep_k<<<16705, 256, 0, stream>>>(x, xb, xf8, Wq, Wk, Wv, wt, wv8, bq, bk, bv, bc);
  gemm_qk_k<<<dim3(512), 256, 0, stream>>>(xb, wt, bc, qk);
  vqs_k<<<dim3(4096), 256, 0, stream>>>(xf8, wv8, bc, vt, qk, Pm);
  pv_k<<<dim3(2048), 256, 0, stream>>>(Pm, vt, xb, gm, out);
}

// Round 21
// 217.163 us; speedup vs baseline: 1.1784x; 1.1784x over previous
//
#include <hip/hip_runtime.h>

typedef unsigned short u16;
typedef unsigned char u8;
typedef __attribute__((ext_vector_type(8))) short bf16x8;
typedef __attribute__((ext_vector_type(4))) float f32x4;
typedef __attribute__((ext_vector_type(4))) int i32x4;
typedef __attribute__((ext_vector_type(8))) int i32x8;

__device__ __forceinline__ u16 f2bf(float f) {
  unsigned u = __builtin_bit_cast(unsigned, f);
  u += 0x7fffu + ((u >> 16) & 1u);
  return (u16)(u >> 16);
}

__device__ __forceinline__ float bf2f(u16 h) {
  unsigned u = ((unsigned)h) << 16;
  return __builtin_bit_cast(float, u);
}

__device__ __forceinline__ unsigned pkbf(float lo, float hi) {
  unsigned r;
  asm("v_cvt_pk_bf16_f32 %0, %1, %2" : "=v"(r) : "v"(lo), "v"(hi));
  return r;
}

__device__ __forceinline__ void gll16(const void* g, void* l) {
  __builtin_amdgcn_global_load_lds((const __attribute__((address_space(1))) void*)g,
                                   (__attribute__((address_space(3))) void*)l, 16, 0, 0);
}

// MX fp8 MFMA with unity scales (e8m0 127 = 2^0): numerically plain fp8, 2.28x rate.
__device__ __forceinline__ f32x4 mfma_fp8_k128(i32x8 a, i32x8 b, f32x4 c) {
  return __builtin_amdgcn_mfma_scale_f32_16x16x128_f8f6f4(
      a, b, c, 0, 0, 0, 0x7f7f7f7f, 0, 0x7f7f7f7f);
}

// ---- prep: x->bf16 + x->fp8  |  Wq/Wk transpose (bf16) + Wv transpose (fp8)  |  bias ----
__global__ void prep_k(const float* __restrict__ x, u16* __restrict__ xb, u8* __restrict__ xf8,
                       const float* __restrict__ Wq, const float* __restrict__ Wk,
                       const float* __restrict__ Wv, u16* __restrict__ wt, u8* __restrict__ wv8,
                       const float* __restrict__ bq, const float* __restrict__ bk,
                       const float* __restrict__ bv, float* __restrict__ bc) {
  __shared__ float tile[64][65];
  const int b = blockIdx.x;
  const int t = threadIdx.x;
  if (b < 16384) {           // x -> bf16 + fp8
    const size_t i = ((size_t)b * 256 + t) * 8;
    float4 a = *(const float4*)(x + i);
    float4 c = *(const float4*)(x + i + 4);
    uint4 u;
    u.x = pkbf(a.x, a.y);
    u.y = pkbf(a.z, a.w);
    u.z = pkbf(c.x, c.y);
    u.w = pkbf(c.z, c.w);
    *(uint4*)(xb + i) = u;
    uint2 v;
    unsigned p0 = __builtin_amdgcn_cvt_pk_fp8_f32(a.x, a.y, 0, false);
    p0 = __builtin_amdgcn_cvt_pk_fp8_f32(a.z, a.w, p0, true);
    unsigned p1 = __builtin_amdgcn_cvt_pk_fp8_f32(c.x, c.y, 0, false);
    p1 = __builtin_amdgcn_cvt_pk_fp8_f32(c.z, c.w, p1, true);
    v.x = p0; v.y = p1;
    *(uint2*)(xf8 + i) = v;
  } else if (b < 16704) {    // weight transpose
    const int tb = b - 16384;
    const int n0 = (tb % 20) * 64;
    const int f0 = (tb / 20) * 64;
    const float* src; int ld, coff;
    if (n0 < 128)      { src = Wq; ld = 128;  coff = n0; }
    else if (n0 < 256) { src = Wk; ld = 128;  coff = n0 - 128; }
    else               { src = Wv; ld = 1024; coff = n0 - 256; }
    const int r = t >> 4, c4 = (t & 15) * 4;
    #pragma unroll
    for (int i = 0; i < 4; ++i) {
      float4 v = *(const float4*)(src + (size_t)(f0 + r + 16 * i) * ld + coff + c4);
      tile[r + 16 * i][c4 + 0] = v.x;
      tile[r + 16 * i][c4 + 1] = v.y;
      tile[r + 16 * i][c4 + 2] = v.z;
      tile[r + 16 * i][c4 + 3] = v.w;
    }
    __syncthreads();
    if (n0 < 256) {          // q/k rows -> wt bf16
      #pragma unroll
      for (int i = 0; i < 4; ++i) {
        const int nr = r + 16 * i;
        ushort4 h;
        h.x = f2bf(tile[c4 + 0][nr]);
        h.y = f2bf(tile[c4 + 1][nr]);
        h.z = f2bf(tile[c4 + 2][nr]);
        h.w = f2bf(tile[c4 + 3][nr]);
        *(ushort4*)(wt + (size_t)(n0 + nr) * 1024 + f0 + c4) = h;
      }
    } else {                 // v rows -> wv8 fp8
      #pragma unroll
      for (int i = 0; i < 4; ++i) {
        const int nr = r + 16 * i;
        unsigned v8 = __builtin_amdgcn_cvt_pk_fp8_f32(tile[c4 + 0][nr], tile[c4 + 1][nr], 0, false);
        v8 = __builtin_amdgcn_cvt_pk_fp8_f32(tile[c4 + 2][nr], tile[c4 + 3][nr], v8, true);
        *(unsigned*)(wv8 + (size_t)(n0 - 256 + nr) * 1024 + f0 + c4) = v8;
      }
    }
  } else {                   // bias concat
    for (int i = t; i < 1280; i += 256)
      bc[i] = (i < 128) ? bq[i] : ((i < 256) ? bk[i - 128] : bv[i - 256]);
  }
}

// ------- merged projection GEMM: blocks 0..511 q/k (bf16), 512..2559 v (MX fp8) -------
__global__ __launch_bounds__(256, 2) void gemm_all_k(
    const u16* __restrict__ xb, const u16* __restrict__ wt,
    const u8* __restrict__ xf8, const u8* __restrict__ wv8,
    const float* __restrict__ bc, u16* __restrict__ qkv, u8* __restrict__ vt) {
  __shared__ char smem[32768];
  char* sAc = smem;
  char* sBc = smem + 16384;
  const int t = threadIdx.x;
  const int w = t >> 6, lane = t & 63;
  const int wr = w >> 1, wc = w & 1;
  const int lm = lane & 15, lg = lane >> 4;
  const f32x4 FZ = {0.f, 0.f, 0.f, 0.f};

  if (blockIdx.x < 512) {
    // ---------- q/k path: [32768,1024]bf16 @ [1024,256] + bias -> qk bf16 ----------
    const int bid = blockIdx.x;
    const int xcd = bid & 7, g = bid >> 3;       // g in 0..63
    const int mb = xcd + 8 * (g >> 1);
    const int nt = g & 1;
    const int m0 = mb * 128;
    const int n0 = nt * 128;

    const int brow = t >> 3;
    const int bcol = 8 * ((t & 7) ^ ((t >> 3) & 7));
    const int kswz = (lm & 7) << 4;
    const u16* ab = xb + (size_t)(m0 + brow) * 1024 + bcol;
    const u16* wb = wt + (size_t)(n0 + brow) * 1024 + bcol;

    f32x4 acc[4][4];
    #pragma unroll
    for (int mi = 0; mi < 4; ++mi)
      #pragma unroll
      for (int ni = 0; ni < 4; ++ni) acc[mi][ni] = FZ;

    for (int kt = 0; kt < 16; ++kt) {
      const int k0 = kt * 64;
      char* da = sAc + w * 1024;
      char* db = sBc + w * 1024;
      #pragma unroll
      for (int i = 0; i < 4; ++i) {
        gll16(ab + (size_t)(32 * i) * 1024 + k0, da + 4096 * i);
        gll16(wb + (size_t)(32 * i) * 1024 + k0, db + 4096 * i);
      }
      __syncthreads();
      #pragma unroll
      for (int ks = 0; ks < 2; ++ks) {
        const int ka = (ks * 64 + lg * 16) ^ kswz;
        bf16x8 aF[4], bF[4];
        #pragma unroll
        for (int mi = 0; mi < 4; ++mi)
          aF[mi] = *(const bf16x8*)(sAc + (wr * 64 + mi * 16 + lm) * 128 + ka);
        #pragma unroll
        for (int ni = 0; ni < 4; ++ni)
          bF[ni] = *(const bf16x8*)(sBc + (wc * 64 + ni * 16 + lm) * 128 + ka);
        #pragma unroll
        for (int mi = 0; mi < 4; ++mi)
          #pragma unroll
          for (int ni = 0; ni < 4; ++ni)
            acc[mi][ni] = __builtin_amdgcn_mfma_f32_16x16x32_bf16(aF[mi], bF[ni], acc[mi][ni], 0, 0, 0);
      }
      __syncthreads();
    }

    #pragma unroll
    for (int ni = 0; ni < 4; ++ni) {
      const int col = n0 + wc * 64 + ni * 16 + lm;
      const float bias = bc[col];
      #pragma unroll
      for (int mi = 0; mi < 4; ++mi) {
        const int r0 = m0 + wr * 64 + mi * 16 + lg * 4;
        #pragma unroll
        for (int j = 0; j < 4; ++j)
          qkv[(size_t)(r0 + j) * 256 + col] = f2bf(acc[mi][ni][j] + bias);
      }
    }
  } else {
    // ---------- v path (MX fp8 K=128): [32768,1024] @ [1024,1024] + bias -> vt fp8 ----------
    const int bid = blockIdx.x - 512;            // 512 % 8 == 0 -> same XCD mapping
    const int xcd = bid & 7, g = bid >> 3;       // g in 0..255
    const int mb = xcd + 8 * (g >> 3);
    const int nt = g & 7;
    const int m0 = mb * 128;
    const int n0 = nt * 128;

    const int brow = t >> 3;
    const int bcol = 16 * ((t & 7) ^ ((t >> 3) & 7));
    const int kswz = (lm & 7) << 4;
    const u8* ab = xf8 + (size_t)(m0 + brow) * 1024 + bcol;
    const u8* wb = wv8 + (size_t)(n0 + brow) * 1024 + bcol;

    f32x4 acc[4][4];
    #pragma unroll
    for (int mi = 0; mi < 4; ++mi)
      #pragma unroll
      for (int ni = 0; ni < 4; ++ni) acc[mi][ni] = FZ;

    for (int kt = 0; kt < 8; ++kt) {
      const int k0 = kt * 128;
      #pragma unroll
      for (int i = 0; i < 4; ++i) {
        gll16(ab + (size_t)(32 * i) * 1024 + k0, sAc + i * 4096 + t * 16);
        gll16(wb + (size_t)(32 * i) * 1024 + k0, sBc + i * 4096 + t * 16);
      }
      __syncthreads();
      i32x8 bF[4];
      #pragma unroll
      for (int ni = 0; ni < 4; ++ni) {
        const char* rb = sBc + (wc * 64 + ni * 16 + lm) * 128;
        i32x4 lo = *(const i32x4*)(rb + ((lg * 32) ^ kswz));
        i32x4 hi = *(const i32x4*)(rb + ((lg * 32 + 16) ^ kswz));
        bF[ni] = __builtin_shufflevector(lo, hi, 0, 1, 2, 3, 4, 5, 6, 7);
      }
      #pragma unroll
      for (int mi = 0; mi < 4; ++mi) {
        const char* ra = sAc + (wr * 64 + mi * 16 + lm) * 128;
        i32x4 lo = *(const i32x4*)(ra + ((lg * 32) ^ kswz));
        i32x4 hi = *(const i32x4*)(ra + ((lg * 32 + 16) ^ kswz));
        i32x8 aF = __builtin_shufflevector(lo, hi, 0, 1, 2, 3, 4, 5, 6, 7);
        #pragma unroll
        for (int ni = 0; ni < 4; ++ni)
          acc[mi][ni] = mfma_fp8_k128(aF, bF[ni], acc[mi][ni]);
      }
      __syncthreads();
    }

    #pragma unroll
    for (int ni = 0; ni < 4; ++ni) {
      const int h = n0 + wc * 64 + ni * 16 + lm;
      const float bias = bc[256 + h];
      #pragma unroll
      for (int mi = 0; mi < 4; ++mi) {
        const int r0 = m0 + wr * 64 + mi * 16 + lg * 4;
        const int bg = r0 >> 10;
        const int sb = r0 & 1023;
        unsigned v32 = __builtin_amdgcn_cvt_pk_fp8_f32(acc[mi][ni][0] + bias,
                                                       acc[mi][ni][1] + bias, 0, false);
        v32 = __builtin_amdgcn_cvt_pk_fp8_f32(acc[mi][ni][2] + bias,
                                              acc[mi][ni][3] + bias, v32, true);
        *(unsigned*)(vt + ((size_t)(bg * 1024 + h) << 10) + sb) = v32;
      }
    }
  }
}

// ---------------- QK^T + exact softmax -> normalized P (fp8 e4m3) ----------------
__global__ __launch_bounds__(512, 2) void qks_k(const u16* __restrict__ qk,
                                                u8* __restrict__ P) {
  __shared__ float smax[8][32];
  __shared__ float ssum[8][32];
  const int t = threadIdx.x;
  const int w = t >> 6, lane = t & 63;
  const int lm = lane & 15, lg = lane >> 4;
  const int bid = blockIdx.x;
  const int qt = (bid >> 3) & 31;
  const int bg = (((bid >> 8) & 3) << 3) | (bid & 7);
  const f32x4 FZ = {0.f, 0.f, 0.f, 0.f};

  bf16x8 qf[2][4];
  #pragma unroll
  for (int qc = 0; qc < 2; ++qc)
    #pragma unroll
    for (int ks = 0; ks < 4; ++ks)
      qf[qc][ks] = *(const bf16x8*)(qk +
          (size_t)(bg * 1024 + qt * 32 + qc * 16 + lm) * 256 + ks * 32 + lg * 8);

  f32x4 sc[8][2];
  #pragma unroll
  for (int ch = 0; ch < 8; ++ch) { sc[ch][0] = FZ; sc[ch][1] = FZ; }
  const u16* kbase = qk + (size_t)(bg * 1024 + w * 128) * 256 + 128;
  #pragma unroll
  for (int ch = 0; ch < 8; ++ch) {
    bf16x8 kf[4];
    #pragma unroll
    for (int ks = 0; ks < 4; ++ks)
      kf[ks] = *(const bf16x8*)(kbase + (size_t)(ch * 16 + lm) * 256 + ks * 32 + lg * 8);
    #pragma unroll
    for (int ks = 0; ks < 4; ++ks) {
      sc[ch][0] = __builtin_amdgcn_mfma_f32_16x16x32_bf16(kf[ks], qf[0][ks], sc[ch][0], 0, 0, 0);
      sc[ch][1] = __builtin_amdgcn_mfma_f32_16x16x32_bf16(kf[ks], qf[1][ks], sc[ch][1], 0, 0, 0);
    }
  }

  float mx[2];
  #pragma unroll
  for (int qc = 0; qc < 2; ++qc) {
    float m = sc[0][qc][0];
    #pragma unroll
    for (int ch = 0; ch < 8; ++ch)
      #pragma unroll
      for (int j = 0; j < 4; ++j) m = fmaxf(m, sc[ch][qc][j]);
    m = fmaxf(m, __shfl_xor(m, 16));
    m = fmaxf(m, __shfl_xor(m, 32));
    mx[qc] = m;
  }
  if (lg == 0) { smax[w][lm] = mx[0]; smax[w][16 + lm] = mx[1]; }
  __syncthreads();
  float gm[2];
  #pragma unroll
  for (int qc = 0; qc < 2; ++qc) {
    float m = smax[0][qc * 16 + lm];
    #pragma unroll
    for (int wp = 1; wp < 8; ++wp) m = fmaxf(m, smax[wp][qc * 16 + lm]);
    gm[qc] = m;
  }

  float ls[2] = {0.f, 0.f};
  #pragma unroll
  for (int ch = 0; ch < 8; ++ch)
    #pragma unroll
    for (int qc = 0; qc < 2; ++qc) {
      f32x4 e;
      #pragma unroll
      for (int j = 0; j < 4; ++j) e[j] = __expf(sc[ch][qc][j] - gm[qc]);
      sc[ch][qc] = e;
      ls[qc] += (e[0] + e[1]) + (e[2] + e[3]);
    }
  #pragma unroll
  for (int qc = 0; qc < 2; ++qc) {
    ls[qc] += __shfl_xor(ls[qc], 16);
    ls[qc] += __shfl_xor(ls[qc], 32);
  }
  if (lg == 0) { ssum[w][lm] = ls[0]; ssum[w][16 + lm] = ls[1]; }
  __syncthreads();
  float inv[2];
  #pragma unroll
  for (int qc = 0; qc < 2; ++qc) {
    float s = ssum[0][qc * 16 + lm];
    #pragma unroll
    for (int wp = 1; wp < 8; ++wp) s += ssum[wp][qc * 16 + lm];
    inv[qc] = 1.0f / s;
  }

  const int s0 = (2 * (lg & 1)) * 16 + lm;
  const int s1 = s0 + 16;
  const bool lo = (lg < 2);
  #pragma unroll
  for (int qc = 0; qc < 2; ++qc) {
    u8* pr = P + ((size_t)(bg * 1024 + qt * 32 + qc * 16 + lm) << 10) + w * 128 + lg * 8;
    #pragma unroll
    for (int c = 0; c < 4; ++c) {
      unsigned ue = __builtin_amdgcn_cvt_pk_fp8_f32(sc[2 * c][qc][0] * inv[qc],
                                                    sc[2 * c][qc][1] * inv[qc], 0, false);
      ue = __builtin_amdgcn_cvt_pk_fp8_f32(sc[2 * c][qc][2] * inv[qc],
                                           sc[2 * c][qc][3] * inv[qc], ue, true);
      unsigned uo = __builtin_amdgcn_cvt_pk_fp8_f32(sc[2 * c + 1][qc][0] * inv[qc],
                                                    sc[2 * c + 1][qc][1] * inv[qc], 0, false);
      uo = __builtin_amdgcn_cvt_pk_fp8_f32(sc[2 * c + 1][qc][2] * inv[qc],
                                           sc[2 * c + 1][qc][3] * inv[qc], uo, true);
      unsigned e0 = __shfl(ue, s0), o0 = __shfl(uo, s0);
      unsigned e1 = __shfl(ue, s1), o1 = __shfl(uo, s1);
      uint2 pw;
      pw.x = lo ? e0 : o0;
      pw.y = lo ? e1 : o1;
      *(uint2*)(pr + c * 32) = pw;
    }
  }
}

// ---------------- PV GEMM (MX fp8 K=128) + epilogue: out = gamma * (P @ V) + xb ----------------
__global__ __launch_bounds__(256, 2) void pv_k(
    const u8* __restrict__ P, const u8* __restrict__ vt,
    const u16* __restrict__ xb, const float* __restrict__ gam,
    float* __restrict__ out) {
  __shared__ u8 sA[128 * 128];
  __shared__ u8 sB[128 * 128];
  char* sAc = (char*)sA;
  char* sBc = (char*)sB;
  const int t = threadIdx.x;
  const int w = t >> 6, lane = t & 63;
  const int wr = w >> 1, wc = w & 1;
  const int lm = lane & 15, lg = lane >> 4;
  const int bid = blockIdx.x;
  const int bg = (((bid >> 9) & 3) << 3) | (bid & 7);
  const int qb = (bid >> 6) & 7;
  const int hb = (bid >> 3) & 7;
  const int m0 = qb * 128, n0 = hb * 128;
  const f32x4 FZ = {0.f, 0.f, 0.f, 0.f};

  const int brow = t >> 3;
  const int bcol = 16 * ((t & 7) ^ ((t >> 3) & 7));
  const int kswz = (lm & 7) << 4;
  const u8* pb = P + ((size_t)(bg * 1024 + m0 + brow) << 10) + bcol;
  const u8* wb = vt + ((size_t)(bg * 1024 + n0 + brow) << 10) + bcol;

  f32x4 acc[4][4];
  #pragma unroll
  for (int mi = 0; mi < 4; ++mi)
    #pragma unroll
    for (int ni = 0; ni < 4; ++ni) acc[mi][ni] = FZ;

  for (int kt = 0; kt < 8; ++kt) {
    const int k0 = kt * 128;
    #pragma unroll
    for (int i = 0; i < 4; ++i) {
      gll16(pb + (size_t)(32 * i) * 1024 + k0, sAc + i * 4096 + t * 16);
      gll16(wb + (size_t)(32 * i) * 1024 + k0, sBc + i * 4096 + t * 16);
    }
    __syncthreads();
    i32x8 bF[4];
    #pragma unroll
    for (int ni = 0; ni < 4; ++ni) {
      const char* rb = sBc + (wc * 64 + ni * 16 + lm) * 128;
      i32x4 lo = *(const i32x4*)(rb + ((lg * 32) ^ kswz));
      i32x4 hi = *(const i32x4*)(rb + ((lg * 32 + 16) ^ kswz));
      bF[ni] = __builtin_shufflevector(lo, hi, 0, 1, 2, 3, 4, 5, 6, 7);
    }
    #pragma unroll
    for (int mi = 0; mi < 4; ++mi) {
      const char* ra = sAc + (wr * 64 + mi * 16 + lm) * 128;
      i32x4 lo = *(const i32x4*)(ra + ((lg * 32) ^ kswz));
      i32x4 hi = *(const i32x4*)(ra + ((lg * 32 + 16) ^ kswz));
      i32x8 aF = __builtin_shufflevector(lo, hi, 0, 1, 2, 3, 4, 5, 6, 7);
      #pragma unroll
      for (int ni = 0; ni < 4; ++ni)
        acc[mi][ni] = mfma_fp8_k128(aF, bF[ni], acc[mi][ni]);
    }
    __syncthreads();
  }

  const float g0 = gam[0];
  #pragma unroll
  for (int mi = 0; mi < 4; ++mi)
    #pragma unroll
    for (int j = 0; j < 4; ++j) {
      const size_t row = (size_t)(bg * 1024 + m0 + wr * 64 + mi * 16 + lg * 4 + j);
      #pragma unroll
      for (int ni = 0; ni < 4; ++ni) {
        const int col = n0 + wc * 64 + ni * 16 + lm;
        const size_t idx = row * 1024 + col;
        __builtin_nontemporal_store(g0 * acc[mi][ni][j] + bf2f(xb[idx]), &out[idx]);
      }
    }
}

extern "C" void kernel_launch(void* const* d_in, const int* in_sizes, int n_in,
                              void* d_out, int out_size, void* d_ws, size_t ws_size,
                              hipStream_t stream) {
  const float* x  = (const float*)d_in[0];
  const float* Wq = (const float*)d_in[1];
  const float* bq = (const float*)d_in[2];
  const float* Wk = (const float*)d_in[3];
  const float* bk = (const float*)d_in[4];
  const float* Wv = (const float*)d_in[5];
  const float* bv = (const float*)d_in[6];
  const float* gm = (const float*)d_in[7];
  float* out = (float*)d_out;

  char* ws = (char*)d_ws;
  u16*   wt  = (u16*)(ws);                 // 524,288 B (q/k rows only)
  float* bc  = (float*)(ws + 524288);      // 5,120 B
  u16*   qk  = (u16*)(ws + 529408);        // 16,777,216 B
  u8*    vt  = (u8*)(ws + 17306624);       // 33,554,432 B (fp8)
  u8*    Pm  = (u8*)(ws + 50861056);       // 33,554,432 B (fp8)
  u16*   xb  = (u16*)(ws + 84415488);      // 67,108,864 B (bf16)
  u8*    xf8 = (u8*)(ws + 151524352);      // 33,554,432 B (fp8)
  u8*    wv8 = (u8*)(ws + 185078784);      // 1,048,576 B

  prep_k<<<16705, 256, 0, stream>>>(x, xb, xf8, Wq, Wk, Wv, wt, wv8, bq, bk, bv, bc);
  gemm_all_k<<<dim3(2560), 256, 0, stream>>>(xb, wt, xf8, wv8, bc, qk, vt);
  qks_k<<<dim3(1024), 512, 0, stream>>>(qk, Pm);
  pv_k<<<dim3(2048), 256, 0, stream>>>(Pm, vt, xb, gm, out);
}